// Round 21
// baseline (97.813 us; speedup 1.0000x reference)
//
#include <hip/hip_runtime.h>
#include <math.h>

// Unfused mul/add everywhere: the np-exact chain (phase 3) requires separately
// rounded mul/add; phases 1-2 are unaffected semantically.
#pragma clang fp contract(off)

// MoE gate: logits = x @ W^T + bias ; softmax ; top-8 ; dense scatter.
// Outputs (float32): vals[16384*8] | idx[16384*8] | dense[16384*64].
//
// r21: r20 (M-rep 4, grid 256, 8 waves/CU) regressed 81.8->91.4us: W-traffic
// halving (-10us) was outweighed by the 8-wave/CU latency cliff (+20us, same
// as r11/r12). This round keeps BOTH levers: 1024-thread block = 16 waves/CU
// AND M-rep 4 (grid 256, W re-read 256MB). K-split 16 (wave K=128, 4 k-tiles).
// VGPR cap is 128 (16 resident waves) -> kt body split into two sequential
// M-pairs (live set ~100 regs); B frags re-loaded per pair (L1/L2 hit).
// part[16][64][33] = 132KB, two-phase reduce, deterministic 16-way pairwise.
//  P2 finish: one wave/row (validated r15+). P3 exact_fix: bit-exact np chain
//  (npyv SSE2/SSE3: reverse in-block, unfused, hadd tree) for near-ties.
// d_ws: [0,512KB) flags ; [512KB,768KB) Wh frag-order ; [768KB,1MB) Wl.

#define NROWS 16384
#define DIM   2048
#define NE    64
#define MARGIN 1e-4f
#define MAXCAND 12
#define WS_WOFF (512 * 1024)

typedef float f32x4 __attribute__((ext_vector_type(4)));
typedef short s16x8 __attribute__((ext_vector_type(8)));

__device__ __forceinline__ void ld16_lds(const float* g, void* l) {
  __builtin_amdgcn_global_load_lds((const __attribute__((address_space(1))) void*)g,
                                   (__attribute__((address_space(3))) void*)l, 16, 0, 0);
}
__device__ __forceinline__ unsigned short bf16_rne(float f) {
  unsigned u = __builtin_bit_cast(unsigned, f);
  u += 0x7FFFu + ((u >> 16) & 1u);
  return (unsigned short)(u >> 16);
}
__device__ __forceinline__ float bf16f(unsigned short h) {
  return __builtin_bit_cast(float, (unsigned)h << 16);
}
__device__ __forceinline__ void cvt8(const f32x4 a, const f32x4 b, s16x8* hi, s16x8* lo) {
#pragma unroll
  for (int j = 0; j < 4; ++j) {
    unsigned short h = bf16_rne(a[j]);
    (*hi)[j] = (short)h; (*lo)[j] = (short)bf16_rne(a[j] - bf16f(h));
  }
#pragma unroll
  for (int j = 0; j < 4; ++j) {
    unsigned short h = bf16_rne(b[j]);
    (*hi)[4 + j] = (short)h; (*lo)[4 + j] = (short)bf16_rne(b[j] - bf16f(h));
  }
}

// ---------------- Phase 0a: W -> split-bf16 in FRAGMENT ORDER ----------------
// Element (e,k): quad n=e>>4, col=e&15; ktile kt=k>>5, j=k&31.
// Frag slot: lane = col | ((j>>3)<<4), elem = j&7.
// Linear: ((kt*4 + n)*64 + lane)*8 + elem  -> B-frag wave-load is contiguous.
__global__ __launch_bounds__(256, 8)
void w_split(const float* __restrict__ w, unsigned short* __restrict__ whf,
             unsigned short* __restrict__ wlf) {
  const int i = blockIdx.x * 256 + threadIdx.x;   // 0..131071
  const int e = i >> 11, k = i & 2047;
  float v = w[i];
  unsigned short h = bf16_rne(v);
  unsigned short lo = bf16_rne(v - bf16f(h));
  const int n = e >> 4, col = e & 15;
  const int kt = k >> 5, j = k & 31;
  const int lane = col | ((j >> 3) << 4);
  const size_t off = (((size_t)(kt << 2) + n) * 64 + lane) * 8 + (j & 7);
  whf[off] = h; wlf[off] = lo;
}

// ---------------- Phase 0b: zero the flag counter ----------
__global__ void zero_flags(int* __restrict__ flags) {
  if (threadIdx.x == 0) flags[0] = 0;
}

// ---------------- Phase 1: split-bf16 MFMA logits, K-split 16, M-rep 4 ------
template <bool USE_WS>
__global__ __launch_bounds__(1024, 1)
void mfma_logits(const float* __restrict__ x, const float* __restrict__ w,
                 const float* __restrict__ bias, float* __restrict__ lg,
                 const unsigned short* __restrict__ whf,
                 const unsigned short* __restrict__ wlf)
{
  __shared__ float part[16][64][33];   // 132 KB, padded; two-phase reduce

  const int t = threadIdx.x;
  const int wv = t >> 6, lane = t & 63;         // wv = K-sixteenth 0..15
  const int rowBase = blockIdx.x << 6;          // 64 rows/block
  const int frow = lane & 15;                   // frag row / frag expert
  const int fk   = (lane >> 4) << 3;            // frag k-chunk: 0,8,16,24
  const size_t q0 = (size_t)wv * 128;           // this wave's K-sixteenth

  const float* xb[4];
#pragma unroll
  for (int m = 0; m < 4; ++m)
    xb[m] = x + (size_t)(rowBase + (m << 4) + frow) * DIM + q0 + fk;
  const float* wb = w + (size_t)frow * DIM + q0 + fk;   // fallback path
  const int ktg0 = wv << 2;                     // global ktile base (0..60)

  f32x4 acc[4][4];
#pragma unroll
  for (int m = 0; m < 4; ++m)
#pragma unroll
    for (int n = 0; n < 4; ++n) acc[m][n] = (f32x4)(0.f);

#pragma unroll 1
  for (int kt = 0; kt < 4; ++kt) {              // 4 k-tiles of 32 per wave
    const int ko = kt << 5;
#pragma unroll
    for (int mp = 0; mp < 2; ++mp) {            // two sequential M-pairs
      s16x8 ah0, al0, ah1, al1;
      {
        f32x4 a0, a1;
        a0 = *(const f32x4*)(xb[2 * mp] + ko);
        a1 = *(const f32x4*)(xb[2 * mp] + ko + 4);
        cvt8(a0, a1, &ah0, &al0);
        a0 = *(const f32x4*)(xb[2 * mp + 1] + ko);
        a1 = *(const f32x4*)(xb[2 * mp + 1] + ko + 4);
        cvt8(a0, a1, &ah1, &al1);
      }
#pragma unroll
      for (int n = 0; n < 4; ++n) {
        s16x8 bh, bl;
        if constexpr (USE_WS) {
          const size_t foff = (((size_t)((ktg0 + kt) << 2) + n) * 64 + lane) * 8;
          bh = *(const s16x8*)(whf + foff);     // contiguous 1KB wave-load
          bl = *(const s16x8*)(wlf + foff);     // (2nd M-pair touch: L1/L2 hit)
        } else {
          const float* wp = wb + (size_t)(n << 4) * DIM + ko;
          f32x4 b0 = *(const f32x4*)(wp);
          f32x4 b1 = *(const f32x4*)(wp + 4);
          cvt8(b0, b1, &bh, &bl);
        }
        const int m0 = 2 * mp, m1 = 2 * mp + 1;
        acc[m0][n] = __builtin_amdgcn_mfma_f32_16x16x32_bf16(al0, bh, acc[m0][n], 0, 0, 0);
        acc[m0][n] = __builtin_amdgcn_mfma_f32_16x16x32_bf16(ah0, bl, acc[m0][n], 0, 0, 0);
        acc[m0][n] = __builtin_amdgcn_mfma_f32_16x16x32_bf16(ah0, bh, acc[m0][n], 0, 0, 0);
        acc[m1][n] = __builtin_amdgcn_mfma_f32_16x16x32_bf16(al1, bh, acc[m1][n], 0, 0, 0);
        acc[m1][n] = __builtin_amdgcn_mfma_f32_16x16x32_bf16(ah1, bl, acc[m1][n], 0, 0, 0);
        acc[m1][n] = __builtin_amdgcn_mfma_f32_16x16x32_bf16(ah1, bh, acc[m1][n], 0, 0, 0);
      }
    }
  }

  // Two-phase cross-K reduce (part[] = 32 rows per phase).
  // D layout: col=lane&15, row=(lane>>4)*4+r (validated r13).
#pragma unroll
  for (int ph = 0; ph < 2; ++ph) {
    if (ph) __syncthreads();                     // prior reduce done
#pragma unroll
    for (int mm = 0; mm < 2; ++mm) {
      const int m = (ph << 1) + mm;
#pragma unroll
      for (int n = 0; n < 4; ++n)
#pragma unroll
        for (int r = 0; r < 4; ++r)
          part[wv][(n << 4) + (lane & 15)][(mm << 4) + ((lane >> 4) << 2) + r] = acc[m][n][r];
    }
    __syncthreads();
    // deterministic 16-way pairwise reduce; coalesced writes (lane -> col)
#pragma unroll
    for (int i = t; i < 2048; i += 1024) {
      const int row = i >> 6, col = i & 63;
      float v0 = ((part[0][col][row] + part[1][col][row])
                + (part[2][col][row] + part[3][col][row]))
               + ((part[4][col][row] + part[5][col][row])
                + (part[6][col][row] + part[7][col][row]));
      float v1 = ((part[8][col][row] + part[9][col][row])
                + (part[10][col][row] + part[11][col][row]))
               + ((part[12][col][row] + part[13][col][row])
                + (part[14][col][row] + part[15][col][row]));
      lg[(size_t)(rowBase + (ph << 5) + row) * NE + col] = (v0 + v1) + bias[col];
    }
  }
}

// ---------------- Phase 2: finish — one wave per row (validated) ---------
__global__ __launch_bounds__(256, 4)
void finish_kernel(float* __restrict__ gate, float* __restrict__ out_vals,
                   float* __restrict__ out_idx, int* __restrict__ flags, int maxf)
{
  const int t    = threadIdx.x;
  const int row  = blockIdx.x * 4 + (t >> 6);
  const int lane = t & 63;                 // lane == expert

  float l = gate[(size_t)row * NE + lane];

  float m = l;
#pragma unroll
  for (int d = 32; d >= 1; d >>= 1) m = fmaxf(m, __shfl_xor(m, d));
  float pe = expf(l - m);
  float s = pe;
#pragma unroll
  for (int d = 32; d >= 1; d >>= 1) s = s + __shfl_xor(s, d);
  float p = pe / s;

  // top-9: lexicographic tournament == serial strict-> lowest-idx scan
  float cur = l;
  float sval[9]; int sidx[9];
  unsigned long long used8 = 0;
#pragma unroll
  for (int k = 0; k < 9; ++k) {
    float v = cur; int i = lane;
#pragma unroll
    for (int d = 1; d < 64; d <<= 1) {
      float ov = __shfl_xor(v, d);
      int   oi = __shfl_xor(i, d);
      bool take = (ov > v) || (ov == v && oi < i);
      v = take ? ov : v;
      i = take ? oi : i;
    }
    sval[k] = v; sidx[k] = i;
    if (k < 8) {
      used8 |= 1ull << i;
      if (lane == i) cur = -INFINITY;
    }
  }

  float myv = 0.f, myi = 0.f;
#pragma unroll
  for (int k = 0; k < 8; ++k) {
    float pv = __shfl(p, sidx[k]);
    if (lane == k) { myv = pv; myi = (float)sidx[k]; }
  }
  if (lane < 8) {
    out_vals[(size_t)row * 8 + lane] = myv;
    out_idx [(size_t)row * 8 + lane] = myi;
  }

  gate[(size_t)row * NE + lane] = ((used8 >> lane) & 1ull) ? p : 0.0f;

  float ming = INFINITY;
#pragma unroll
  for (int k = 1; k < 9; ++k) ming = fminf(ming, sval[k - 1] - sval[k]);
  if (ming < MARGIN && maxf > 0) {
    unsigned long long cmask = __ballot(l >= sval[7] - MARGIN);
    int n = __popcll(cmask);
    if (n <= MAXCAND) {   // overflow: keep approx result (~1e-9 probability)
      int slot = 0;
      if (lane == 0) slot = atomicAdd(flags, 1);
      slot = __shfl(slot, 0);
      if (slot < maxf) {
        int* rec = flags + 4 + slot * 32;
        if (lane == 0) { rec[0] = row; rec[1] = n; }
        if ((cmask >> lane) & 1ull) {
          int pos = __popcll(cmask & ((1ull << lane) - 1ull));  // ascending e
          rec[2 + pos] = lane;
          ((float*)(rec + 14))[pos] = p;
        }
      }
    }
  }
}

// ---------------- Phase 3: np-exact fixup for flagged rows (unchanged) -------
__global__ __launch_bounds__(64, 1)
void exact_fix(const float* __restrict__ x, const float* __restrict__ w,
               const float* __restrict__ bias, const int* __restrict__ flags,
               int maxf, float* __restrict__ out_vals, float* __restrict__ out_idx,
               float* __restrict__ gate)
{
  __shared__ float xs_[DIM];                 // 8 KB
  __shared__ float wl_[MAXCAND * DIM];       // 96 KB
  __shared__ float exl[MAXCAND];

  int count = flags[0]; if (count > maxf) count = maxf;
  const int lane = threadIdx.x;

  for (int recI = blockIdx.x; recI < count; recI += (int)gridDim.x) {
    const int* rec = flags + 4 + recI * 32;
    const int row = rec[0], n = rec[1];

#pragma unroll
    for (int i = 0; i < 8; ++i)
      ld16_lds(x + (size_t)row * DIM + i * 256 + lane * 4, &xs_[i * 256 + lane * 4]);
    for (int c = 0; c < n; ++c)
#pragma unroll
      for (int i = 0; i < 8; ++i)
        ld16_lds(w + (size_t)rec[2 + c] * DIM + i * 256 + lane * 4,
                 &wl_[c * DIM + i * 256 + lane * 4]);
    asm volatile("s_waitcnt vmcnt(0)" ::: "memory");
    __builtin_amdgcn_s_barrier();

    // np-exact chain: lane = cand*4 + npLane j; reverse in-block, unfused
    const int c = lane >> 2, jj = lane & 3;
    const int cw = (c < n) ? c : 0;
    const float* wrow = &wl_[cw * DIM];
    float a = 0.f;
#pragma unroll 4
    for (int b = 0; b < 128; ++b) {
      const int k = (b << 4) + jj;
      a = a + xs_[k + 12] * wrow[k + 12];
      a = a + xs_[k + 8]  * wrow[k + 8];
      a = a + xs_[k + 4]  * wrow[k + 4];
      a = a + xs_[k]      * wrow[k];
    }
    // SSE3 hadd tree: (L0+L1)+(L2+L3)  (f32 add is commutative-exact)
    float o1 = __shfl_xor(a, 1);
    float s01 = a + o1;
    float o2 = __shfl_xor(s01, 2);
    float tot = (s01 + o2) + bias[rec[2 + cw]];
    if (jj == 0 && c < n) exl[c] = tot;
    __syncthreads();

    if (lane == 0) {
      unsigned used = 0;
      const float* cp = (const float*)(rec + 14);
      for (int k = 0; k < 8; ++k) {
        float best = -INFINITY; int bi = 0;
        for (int c2 = 0; c2 < n; ++c2) {
          bool ok = (((used >> c2) & 1u) == 0u) && (exl[c2] > best);
          best = ok ? exl[c2] : best;
          bi   = ok ? c2      : bi;
        }
        used |= 1u << bi;
        out_vals[(size_t)row * 8 + k] = cp[bi];
        out_idx [(size_t)row * 8 + k] = (float)rec[2 + bi];
      }
      for (int c2 = 0; c2 < n; ++c2)
        gate[(size_t)row * NE + rec[2 + c2]] = ((used >> c2) & 1u) ? cp[c2] : 0.f;
    }
    __syncthreads();
  }
}

extern "C" void kernel_launch(void* const* d_in, const int* in_sizes, int n_in,
                              void* d_out, int out_size, void* d_ws, size_t ws_size,
                              hipStream_t stream) {
  const float* x    = (const float*)d_in[0];
  const float* w    = (const float*)d_in[1];
  const float* bias = (const float*)d_in[2];
  float* out   = (float*)d_out;
  float* vals  = out;                       // 16384*8
  float* idx   = out + (size_t)NROWS * 8;   // 16384*8
  float* dense = out + (size_t)NROWS * 16;  // 16384*64 (P1 logit scratch)
  (void)in_sizes; (void)n_in; (void)out_size;

  const bool use_ws_w = ws_size >= WS_WOFF + (size_t)NE * DIM * 4;  // 1 MB
  int maxf = 0;
  if (ws_size >= 16 + 32 * 4) {
    size_t cap = (ws_size / 4 - 4) / 32;
    if (cap > 2048) cap = 2048;
    if (use_ws_w) { size_t cap2 = (WS_WOFF / 4 - 4) / 32; if (cap > cap2) cap = cap2; }
    maxf = (int)cap;
  }
  int* flags = (int*)d_ws;
  unsigned short* whf = (unsigned short*)((char*)d_ws + WS_WOFF);
  unsigned short* wlf = whf + (size_t)NE * DIM;

  if (use_ws_w) {
    w_split<<<dim3(NE * DIM / 256), dim3(256), 0, stream>>>(w, whf, wlf);
    mfma_logits<true><<<dim3(NROWS / 64), dim3(1024), 0, stream>>>(x, w, bias, dense, whf, wlf);
  } else {
    mfma_logits<false><<<dim3(NROWS / 64), dim3(1024), 0, stream>>>(x, w, bias, dense, whf, wlf);
  }
  if (maxf > 0) zero_flags<<<dim3(1), dim3(64), 0, stream>>>(flags);
  finish_kernel<<<dim3(NROWS / 4), dim3(256), 0, stream>>>(dense, vals, idx, flags, maxf);
  if (maxf > 0)
    exact_fix<<<dim3(128), dim3(64), 0, stream>>>(x, w, bias, flags, maxf, vals, idx, dense);
}

// Round 22
// 91.447 us; speedup vs baseline: 1.0696x; 1.0696x over previous
//
#include <hip/hip_runtime.h>
#include <math.h>

// Unfused mul/add everywhere: the np-exact chain (phase 3) requires separately
// rounded mul/add; phases 1-2 are unaffected semantically.
#pragma clang fp contract(off)

// MoE gate: logits = x @ W^T + bias ; softmax ; top-8 ; dense scatter.
// Outputs (float32): vals[16384*8] | idx[16384*8] | dense[16384*64].
//
// r22 = r19 structure (M-rep 2, 512thr, 2 blk/CU, 16 waves/CU — best at
// 81.8us; r20/r21's M-rep 4 variants both regressed: 8-wave latency cliff
// and VGPR spill respectively) + ONE change: x fragment loads are
// NON-TEMPORAL. x is read exactly once; letting it churn L2's LRU evicts the
// 1MB W-split that 512 blocks re-read (512MB of traffic pushed to L3). With
// x marked nt, W stays L2-resident -> W re-reads become L2 hits.
// Also: zero_flags micro-kernel instead of hipMemsetAsync (r19's fill showed
// ~76us dispatches in rocprof top-5).
//  P2 finish: one wave/row (validated r15+). P3 exact_fix: bit-exact np chain
//  (npyv SSE2/SSE3: reverse in-block, unfused, hadd tree) for near-ties.
// d_ws: [0,512KB) flags ; [512KB,768KB) Wh frag-order ; [768KB,1MB) Wl.

#define NROWS 16384
#define DIM   2048
#define NE    64
#define MARGIN 1e-4f
#define MAXCAND 12
#define WS_WOFF (512 * 1024)

typedef float f32x4 __attribute__((ext_vector_type(4)));
typedef short s16x8 __attribute__((ext_vector_type(8)));

__device__ __forceinline__ void ld16_lds(const float* g, void* l) {
  __builtin_amdgcn_global_load_lds((const __attribute__((address_space(1))) void*)g,
                                   (__attribute__((address_space(3))) void*)l, 16, 0, 0);
}
__device__ __forceinline__ unsigned short bf16_rne(float f) {
  unsigned u = __builtin_bit_cast(unsigned, f);
  u += 0x7FFFu + ((u >> 16) & 1u);
  return (unsigned short)(u >> 16);
}
__device__ __forceinline__ float bf16f(unsigned short h) {
  return __builtin_bit_cast(float, (unsigned)h << 16);
}
__device__ __forceinline__ void cvt8(const f32x4 a, const f32x4 b, s16x8* hi, s16x8* lo) {
#pragma unroll
  for (int j = 0; j < 4; ++j) {
    unsigned short h = bf16_rne(a[j]);
    (*hi)[j] = (short)h; (*lo)[j] = (short)bf16_rne(a[j] - bf16f(h));
  }
#pragma unroll
  for (int j = 0; j < 4; ++j) {
    unsigned short h = bf16_rne(b[j]);
    (*hi)[4 + j] = (short)h; (*lo)[4 + j] = (short)bf16_rne(b[j] - bf16f(h));
  }
}

// ---------------- Phase 0a: W -> split-bf16 in FRAGMENT ORDER ----------------
// Element (e,k): quad n=e>>4, col=e&15; ktile kt=k>>5, j=k&31.
// Frag slot: lane = col | ((j>>3)<<4), elem = j&7.
// Linear: ((kt*4 + n)*64 + lane)*8 + elem  -> B-frag wave-load is contiguous.
__global__ __launch_bounds__(256, 8)
void w_split(const float* __restrict__ w, unsigned short* __restrict__ whf,
             unsigned short* __restrict__ wlf) {
  const int i = blockIdx.x * 256 + threadIdx.x;   // 0..131071
  const int e = i >> 11, k = i & 2047;
  float v = w[i];
  unsigned short h = bf16_rne(v);
  unsigned short lo = bf16_rne(v - bf16f(h));
  const int n = e >> 4, col = e & 15;
  const int kt = k >> 5, j = k & 31;
  const int lane = col | ((j >> 3) << 4);
  const size_t off = (((size_t)(kt << 2) + n) * 64 + lane) * 8 + (j & 7);
  whf[off] = h; wlf[off] = lo;
}

// ---------------- Phase 0b: zero the flag counter ----------
__global__ void zero_flags(int* __restrict__ flags) {
  if (threadIdx.x == 0) flags[0] = 0;
}

// ---------------- Phase 1: split-bf16 MFMA logits, K-split 8, M-rep 2 -------
template <bool USE_WS>
__global__ __launch_bounds__(512, 4)
void mfma_logits(const float* __restrict__ x, const float* __restrict__ w,
                 const float* __restrict__ bias, float* __restrict__ lg,
                 const unsigned short* __restrict__ whf,
                 const unsigned short* __restrict__ wlf)
{
  __shared__ float part[8][64][33];   // ~67 KB, padded (reduce bank conflict)

  const int t = threadIdx.x;
  const int wv = t >> 6, lane = t & 63;         // wv = K-eighth 0..7
  const int rowBase = blockIdx.x << 5;          // 32 rows/block
  const int frow = lane & 15;                   // frag row / frag expert
  const int fk   = (lane >> 4) << 3;            // frag k-chunk: 0,8,16,24
  const size_t q0 = (size_t)wv * 256;           // this wave's K-eighth

  const float* xb0 = x + (size_t)(rowBase + frow) * DIM + q0 + fk;
  const float* xb1 = xb0 + (size_t)16 * DIM;    // second row-tile
  const float* wb = w + (size_t)frow * DIM + q0 + fk;   // fallback path
  const int ktg0 = wv << 3;                     // global ktile base

  f32x4 acc[2][4];
#pragma unroll
  for (int m = 0; m < 2; ++m)
#pragma unroll
    for (int n = 0; n < 4; ++n) acc[m][n] = (f32x4)(0.f);

#pragma unroll 2
  for (int kt = 0; kt < 8; ++kt) {              // 8 k-tiles of 32 per eighth
    const int ko = kt << 5;
    s16x8 ah0, al0, ah1, al1;
    {
      // NON-TEMPORAL x loads: read-once stream must not evict W from L2.
      f32x4 a0 = __builtin_nontemporal_load((const f32x4*)(xb0 + ko));
      f32x4 a1 = __builtin_nontemporal_load((const f32x4*)(xb0 + ko + 4));
      cvt8(a0, a1, &ah0, &al0);
      f32x4 c0 = __builtin_nontemporal_load((const f32x4*)(xb1 + ko));
      f32x4 c1 = __builtin_nontemporal_load((const f32x4*)(xb1 + ko + 4));
      cvt8(c0, c1, &ah1, &al1);
    }
#pragma unroll
    for (int n = 0; n < 4; ++n) {
      s16x8 bh, bl;
      if constexpr (USE_WS) {
        const size_t foff = (((size_t)((ktg0 + kt) << 2) + n) * 64 + lane) * 8;
        bh = *(const s16x8*)(whf + foff);       // contiguous 1KB wave-load
        bl = *(const s16x8*)(wlf + foff);
      } else {
        const float* wp = wb + (size_t)(n << 4) * DIM + ko;
        f32x4 b0 = *(const f32x4*)(wp);
        f32x4 b1 = *(const f32x4*)(wp + 4);
        cvt8(b0, b1, &bh, &bl);
      }
      acc[0][n] = __builtin_amdgcn_mfma_f32_16x16x32_bf16(al0, bh, acc[0][n], 0, 0, 0);
      acc[0][n] = __builtin_amdgcn_mfma_f32_16x16x32_bf16(ah0, bl, acc[0][n], 0, 0, 0);
      acc[0][n] = __builtin_amdgcn_mfma_f32_16x16x32_bf16(ah0, bh, acc[0][n], 0, 0, 0);
      acc[1][n] = __builtin_amdgcn_mfma_f32_16x16x32_bf16(al1, bh, acc[1][n], 0, 0, 0);
      acc[1][n] = __builtin_amdgcn_mfma_f32_16x16x32_bf16(ah1, bl, acc[1][n], 0, 0, 0);
      acc[1][n] = __builtin_amdgcn_mfma_f32_16x16x32_bf16(ah1, bh, acc[1][n], 0, 0, 0);
    }
  }

  // D layout: col=lane&15, row=(lane>>4)*4+r (validated r13)
#pragma unroll
  for (int m = 0; m < 2; ++m)
#pragma unroll
    for (int n = 0; n < 4; ++n)
#pragma unroll
      for (int r = 0; r < 4; ++r)
        part[wv][(n << 4) + (lane & 15)][(m << 4) + ((lane >> 4) << 2) + r] = acc[m][n][r];
  __syncthreads();

  // deterministic 8-way pairwise reduce; coalesced writes (lane -> col)
#pragma unroll
  for (int i = t; i < 2048; i += 512) {
    const int row = i >> 6, col = i & 63;
    float v = ((part[0][col][row] + part[1][col][row])
             + (part[2][col][row] + part[3][col][row]))
            + ((part[4][col][row] + part[5][col][row])
             + (part[6][col][row] + part[7][col][row]));
    lg[(size_t)(rowBase + row) * NE + col] = v + bias[col];
  }
}

// ---------------- Phase 2: finish — one wave per row (validated) ---------
__global__ __launch_bounds__(256, 4)
void finish_kernel(float* __restrict__ gate, float* __restrict__ out_vals,
                   float* __restrict__ out_idx, int* __restrict__ flags, int maxf)
{
  const int t    = threadIdx.x;
  const int row  = blockIdx.x * 4 + (t >> 6);
  const int lane = t & 63;                 // lane == expert

  float l = gate[(size_t)row * NE + lane];

  float m = l;
#pragma unroll
  for (int d = 32; d >= 1; d >>= 1) m = fmaxf(m, __shfl_xor(m, d));
  float pe = expf(l - m);
  float s = pe;
#pragma unroll
  for (int d = 32; d >= 1; d >>= 1) s = s + __shfl_xor(s, d);
  float p = pe / s;

  // top-9: lexicographic tournament == serial strict-> lowest-idx scan
  float cur = l;
  float sval[9]; int sidx[9];
  unsigned long long used8 = 0;
#pragma unroll
  for (int k = 0; k < 9; ++k) {
    float v = cur; int i = lane;
#pragma unroll
    for (int d = 1; d < 64; d <<= 1) {
      float ov = __shfl_xor(v, d);
      int   oi = __shfl_xor(i, d);
      bool take = (ov > v) || (ov == v && oi < i);
      v = take ? ov : v;
      i = take ? oi : i;
    }
    sval[k] = v; sidx[k] = i;
    if (k < 8) {
      used8 |= 1ull << i;
      if (lane == i) cur = -INFINITY;
    }
  }

  float myv = 0.f, myi = 0.f;
#pragma unroll
  for (int k = 0; k < 8; ++k) {
    float pv = __shfl(p, sidx[k]);
    if (lane == k) { myv = pv; myi = (float)sidx[k]; }
  }
  if (lane < 8) {
    out_vals[(size_t)row * 8 + lane] = myv;
    out_idx [(size_t)row * 8 + lane] = myi;
  }

  gate[(size_t)row * NE + lane] = ((used8 >> lane) & 1ull) ? p : 0.0f;

  float ming = INFINITY;
#pragma unroll
  for (int k = 1; k < 9; ++k) ming = fminf(ming, sval[k - 1] - sval[k]);
  if (ming < MARGIN && maxf > 0) {
    unsigned long long cmask = __ballot(l >= sval[7] - MARGIN);
    int n = __popcll(cmask);
    if (n <= MAXCAND) {   // overflow: keep approx result (~1e-9 probability)
      int slot = 0;
      if (lane == 0) slot = atomicAdd(flags, 1);
      slot = __shfl(slot, 0);
      if (slot < maxf) {
        int* rec = flags + 4 + slot * 32;
        if (lane == 0) { rec[0] = row; rec[1] = n; }
        if ((cmask >> lane) & 1ull) {
          int pos = __popcll(cmask & ((1ull << lane) - 1ull));  // ascending e
          rec[2 + pos] = lane;
          ((float*)(rec + 14))[pos] = p;
        }
      }
    }
  }
}

// ---------------- Phase 3: np-exact fixup for flagged rows (unchanged) -------
__global__ __launch_bounds__(64, 1)
void exact_fix(const float* __restrict__ x, const float* __restrict__ w,
               const float* __restrict__ bias, const int* __restrict__ flags,
               int maxf, float* __restrict__ out_vals, float* __restrict__ out_idx,
               float* __restrict__ gate)
{
  __shared__ float xs_[DIM];                 // 8 KB
  __shared__ float wl_[MAXCAND * DIM];       // 96 KB
  __shared__ float exl[MAXCAND];

  int count = flags[0]; if (count > maxf) count = maxf;
  const int lane = threadIdx.x;

  for (int recI = blockIdx.x; recI < count; recI += (int)gridDim.x) {
    const int* rec = flags + 4 + recI * 32;
    const int row = rec[0], n = rec[1];

#pragma unroll
    for (int i = 0; i < 8; ++i)
      ld16_lds(x + (size_t)row * DIM + i * 256 + lane * 4, &xs_[i * 256 + lane * 4]);
    for (int c = 0; c < n; ++c)
#pragma unroll
      for (int i = 0; i < 8; ++i)
        ld16_lds(w + (size_t)rec[2 + c] * DIM + i * 256 + lane * 4,
                 &wl_[c * DIM + i * 256 + lane * 4]);
    asm volatile("s_waitcnt vmcnt(0)" ::: "memory");
    __builtin_amdgcn_s_barrier();

    // np-exact chain: lane = cand*4 + npLane j; reverse in-block, unfused
    const int c = lane >> 2, jj = lane & 3;
    const int cw = (c < n) ? c : 0;
    const float* wrow = &wl_[cw * DIM];
    float a = 0.f;
#pragma unroll 4
    for (int b = 0; b < 128; ++b) {
      const int k = (b << 4) + jj;
      a = a + xs_[k + 12] * wrow[k + 12];
      a = a + xs_[k + 8]  * wrow[k + 8];
      a = a + xs_[k + 4]  * wrow[k + 4];
      a = a + xs_[k]      * wrow[k];
    }
    // SSE3 hadd tree: (L0+L1)+(L2+L3)  (f32 add is commutative-exact)
    float o1 = __shfl_xor(a, 1);
    float s01 = a + o1;
    float o2 = __shfl_xor(s01, 2);
    float tot = (s01 + o2) + bias[rec[2 + cw]];
    if (jj == 0 && c < n) exl[c] = tot;
    __syncthreads();

    if (lane == 0) {
      unsigned used = 0;
      const float* cp = (const float*)(rec + 14);
      for (int k = 0; k < 8; ++k) {
        float best = -INFINITY; int bi = 0;
        for (int c2 = 0; c2 < n; ++c2) {
          bool ok = (((used >> c2) & 1u) == 0u) && (exl[c2] > best);
          best = ok ? exl[c2] : best;
          bi   = ok ? c2      : bi;
        }
        used |= 1u << bi;
        out_vals[(size_t)row * 8 + k] = cp[bi];
        out_idx [(size_t)row * 8 + k] = (float)rec[2 + bi];
      }
      for (int c2 = 0; c2 < n; ++c2)
        gate[(size_t)row * NE + rec[2 + c2]] = ((used >> c2) & 1u) ? cp[c2] : 0.f;
    }
    __syncthreads();
  }
}

extern "C" void kernel_launch(void* const* d_in, const int* in_sizes, int n_in,
                              void* d_out, int out_size, void* d_ws, size_t ws_size,
                              hipStream_t stream) {
  const float* x    = (const float*)d_in[0];
  const float* w    = (const float*)d_in[1];
  const float* bias = (const float*)d_in[2];
  float* out   = (float*)d_out;
  float* vals  = out;                       // 16384*8
  float* idx   = out + (size_t)NROWS * 8;   // 16384*8
  float* dense = out + (size_t)NROWS * 16;  // 16384*64 (P1 logit scratch)
  (void)in_sizes; (void)n_in; (void)out_size;

  const bool use_ws_w = ws_size >= WS_WOFF + (size_t)NE * DIM * 4;  // 1 MB
  int maxf = 0;
  if (ws_size >= 16 + 32 * 4) {
    size_t cap = (ws_size / 4 - 4) / 32;
    if (cap > 2048) cap = 2048;
    if (use_ws_w) { size_t cap2 = (WS_WOFF / 4 - 4) / 32; if (cap > cap2) cap = cap2; }
    maxf = (int)cap;
  }
  int* flags = (int*)d_ws;
  unsigned short* whf = (unsigned short*)((char*)d_ws + WS_WOFF);
  unsigned short* wlf = whf + (size_t)NE * DIM;

  if (use_ws_w) {
    w_split<<<dim3(NE * DIM / 256), dim3(256), 0, stream>>>(w, whf, wlf);
    mfma_logits<true><<<dim3(NROWS / 32), dim3(512), 0, stream>>>(x, w, bias, dense, whf, wlf);
  } else {
    mfma_logits<false><<<dim3(NROWS / 32), dim3(512), 0, stream>>>(x, w, bias, dense, whf, wlf);
  }
  if (maxf > 0) zero_flags<<<dim3(1), dim3(64), 0, stream>>>(flags);
  finish_kernel<<<dim3(NROWS / 4), dim3(256), 0, stream>>>(dense, vals, idx, flags, maxf);
  if (maxf > 0)
    exact_fix<<<dim3(128), dim3(64), 0, stream>>>(x, w, bias, flags, maxf, vals, idx, dense);
}

// Round 23
// 81.485 us; speedup vs baseline: 1.2004x; 1.1223x over previous
//
#include <hip/hip_runtime.h>
#include <math.h>

// Unfused mul/add everywhere: the np-exact chain (phase 3) requires separately
// rounded mul/add; phases 1-2 are unaffected semantically.
#pragma clang fp contract(off)

// MoE gate: logits = x @ W^T + bias ; softmax ; top-8 ; dense scatter.
// Outputs (float32): vals[16384*8] | idx[16384*8] | dense[16384*64].
//
// r23 = EXACT r19 revert (best measured: 81.8us). Exploration record:
//  r18 (K-split 8, 80% occ)            -> flat (95us): not latency/TLP-bound
//  r19 (frag-order W, M-rep 2, 16w/CU) -> BEST 81.8us
//  r20 (M-rep 4, 8 waves/CU)           -> 91.4 (occupancy cliff)
//  r21 (M-rep 4, 16 waves, 1024thr)    -> 97.8 (VGPR spill, WRITE 56MB)
//  r22 (r19 + nt x-loads + zero_flags) -> 91.4 (nt killed x's L2/L3 hits)
// All levers away from r19 point uphill; this validates the revert.
//  P1 mfma_logits: split-bf16 3-pass MFMA, K-split 8, M-rep 2, frag-order W.
//  P2 finish: one wave/row softmax/top-8/scatter (validated r15+).
//  P3 exact_fix: bit-exact np chain (npyv SSE2/SSE3: reverse in-block,
//     unfused, hadd tree) for flagged near-tie rows (gap < 1e-4).
// d_ws: [0,512KB) flags ; [512KB,768KB) Wh frag-order ; [768KB,1MB) Wl.

#define NROWS 16384
#define DIM   2048
#define NE    64
#define MARGIN 1e-4f
#define MAXCAND 12
#define WS_WOFF (512 * 1024)

typedef float f32x4 __attribute__((ext_vector_type(4)));
typedef short s16x8 __attribute__((ext_vector_type(8)));

__device__ __forceinline__ void ld16_lds(const float* g, void* l) {
  __builtin_amdgcn_global_load_lds((const __attribute__((address_space(1))) void*)g,
                                   (__attribute__((address_space(3))) void*)l, 16, 0, 0);
}
__device__ __forceinline__ unsigned short bf16_rne(float f) {
  unsigned u = __builtin_bit_cast(unsigned, f);
  u += 0x7FFFu + ((u >> 16) & 1u);
  return (unsigned short)(u >> 16);
}
__device__ __forceinline__ float bf16f(unsigned short h) {
  return __builtin_bit_cast(float, (unsigned)h << 16);
}
__device__ __forceinline__ void cvt8(const f32x4 a, const f32x4 b, s16x8* hi, s16x8* lo) {
#pragma unroll
  for (int j = 0; j < 4; ++j) {
    unsigned short h = bf16_rne(a[j]);
    (*hi)[j] = (short)h; (*lo)[j] = (short)bf16_rne(a[j] - bf16f(h));
  }
#pragma unroll
  for (int j = 0; j < 4; ++j) {
    unsigned short h = bf16_rne(b[j]);
    (*hi)[4 + j] = (short)h; (*lo)[4 + j] = (short)bf16_rne(b[j] - bf16f(h));
  }
}

// ---------------- Phase 0: W -> split-bf16 in FRAGMENT ORDER ----------------
// Element (e,k): quad n=e>>4, col=e&15; ktile kt=k>>5, j=k&31.
// Frag slot: lane = col | ((j>>3)<<4), elem = j&7.
// Linear: ((kt*4 + n)*64 + lane)*8 + elem  -> B-frag wave-load is contiguous.
__global__ __launch_bounds__(256, 8)
void w_split(const float* __restrict__ w, unsigned short* __restrict__ whf,
             unsigned short* __restrict__ wlf) {
  const int i = blockIdx.x * 256 + threadIdx.x;   // 0..131071
  const int e = i >> 11, k = i & 2047;
  float v = w[i];
  unsigned short h = bf16_rne(v);
  unsigned short lo = bf16_rne(v - bf16f(h));
  const int n = e >> 4, col = e & 15;
  const int kt = k >> 5, j = k & 31;
  const int lane = col | ((j >> 3) << 4);
  const size_t off = (((size_t)(kt << 2) + n) * 64 + lane) * 8 + (j & 7);
  whf[off] = h; wlf[off] = lo;
}

// ---------------- Phase 1: split-bf16 MFMA logits, K-split 8, M-rep 2 -------
template <bool USE_WS>
__global__ __launch_bounds__(512, 4)
void mfma_logits(const float* __restrict__ x, const float* __restrict__ w,
                 const float* __restrict__ bias, float* __restrict__ lg,
                 const unsigned short* __restrict__ whf,
                 const unsigned short* __restrict__ wlf)
{
  __shared__ float part[8][64][33];   // ~67 KB, padded (reduce bank conflict)

  const int t = threadIdx.x;
  const int wv = t >> 6, lane = t & 63;         // wv = K-eighth 0..7
  const int rowBase = blockIdx.x << 5;          // 32 rows/block
  const int frow = lane & 15;                   // frag row / frag expert
  const int fk   = (lane >> 4) << 3;            // frag k-chunk: 0,8,16,24
  const size_t q0 = (size_t)wv * 256;           // this wave's K-eighth

  const float* xb0 = x + (size_t)(rowBase + frow) * DIM + q0 + fk;
  const float* xb1 = xb0 + (size_t)16 * DIM;    // second row-tile
  const float* wb = w + (size_t)frow * DIM + q0 + fk;   // fallback path
  const int ktg0 = wv << 3;                     // global ktile base

  f32x4 acc[2][4];
#pragma unroll
  for (int m = 0; m < 2; ++m)
#pragma unroll
    for (int n = 0; n < 4; ++n) acc[m][n] = (f32x4)(0.f);

#pragma unroll 2
  for (int kt = 0; kt < 8; ++kt) {              // 8 k-tiles of 32 per eighth
    const int ko = kt << 5;
    s16x8 ah0, al0, ah1, al1;
    {
      f32x4 a0 = *(const f32x4*)(xb0 + ko);
      f32x4 a1 = *(const f32x4*)(xb0 + ko + 4);
      cvt8(a0, a1, &ah0, &al0);
      f32x4 c0 = *(const f32x4*)(xb1 + ko);
      f32x4 c1 = *(const f32x4*)(xb1 + ko + 4);
      cvt8(c0, c1, &ah1, &al1);
    }
#pragma unroll
    for (int n = 0; n < 4; ++n) {
      s16x8 bh, bl;
      if constexpr (USE_WS) {
        const size_t foff = (((size_t)((ktg0 + kt) << 2) + n) * 64 + lane) * 8;
        bh = *(const s16x8*)(whf + foff);       // contiguous 1KB wave-load
        bl = *(const s16x8*)(wlf + foff);
      } else {
        const float* wp = wb + (size_t)(n << 4) * DIM + ko;
        f32x4 b0 = *(const f32x4*)(wp);
        f32x4 b1 = *(const f32x4*)(wp + 4);
        cvt8(b0, b1, &bh, &bl);
      }
      acc[0][n] = __builtin_amdgcn_mfma_f32_16x16x32_bf16(al0, bh, acc[0][n], 0, 0, 0);
      acc[0][n] = __builtin_amdgcn_mfma_f32_16x16x32_bf16(ah0, bl, acc[0][n], 0, 0, 0);
      acc[0][n] = __builtin_amdgcn_mfma_f32_16x16x32_bf16(ah0, bh, acc[0][n], 0, 0, 0);
      acc[1][n] = __builtin_amdgcn_mfma_f32_16x16x32_bf16(al1, bh, acc[1][n], 0, 0, 0);
      acc[1][n] = __builtin_amdgcn_mfma_f32_16x16x32_bf16(ah1, bl, acc[1][n], 0, 0, 0);
      acc[1][n] = __builtin_amdgcn_mfma_f32_16x16x32_bf16(ah1, bh, acc[1][n], 0, 0, 0);
    }
  }

  // D layout: col=lane&15, row=(lane>>4)*4+r (validated r13)
#pragma unroll
  for (int m = 0; m < 2; ++m)
#pragma unroll
    for (int n = 0; n < 4; ++n)
#pragma unroll
      for (int r = 0; r < 4; ++r)
        part[wv][(n << 4) + (lane & 15)][(m << 4) + ((lane >> 4) << 2) + r] = acc[m][n][r];
  __syncthreads();

  // deterministic 8-way pairwise reduce; coalesced writes (lane -> col)
#pragma unroll
  for (int i = t; i < 2048; i += 512) {
    const int row = i >> 6, col = i & 63;
    float v = ((part[0][col][row] + part[1][col][row])
             + (part[2][col][row] + part[3][col][row]))
            + ((part[4][col][row] + part[5][col][row])
             + (part[6][col][row] + part[7][col][row]));
    lg[(size_t)(rowBase + row) * NE + col] = v + bias[col];
  }
}

// ---------------- Phase 2: finish — one wave per row (validated) ---------
__global__ __launch_bounds__(256, 4)
void finish_kernel(float* __restrict__ gate, float* __restrict__ out_vals,
                   float* __restrict__ out_idx, int* __restrict__ flags, int maxf)
{
  const int t    = threadIdx.x;
  const int row  = blockIdx.x * 4 + (t >> 6);
  const int lane = t & 63;                 // lane == expert

  float l = gate[(size_t)row * NE + lane];

  float m = l;
#pragma unroll
  for (int d = 32; d >= 1; d >>= 1) m = fmaxf(m, __shfl_xor(m, d));
  float pe = expf(l - m);
  float s = pe;
#pragma unroll
  for (int d = 32; d >= 1; d >>= 1) s = s + __shfl_xor(s, d);
  float p = pe / s;

  // top-9: lexicographic tournament == serial strict-> lowest-idx scan
  float cur = l;
  float sval[9]; int sidx[9];
  unsigned long long used8 = 0;
#pragma unroll
  for (int k = 0; k < 9; ++k) {
    float v = cur; int i = lane;
#pragma unroll
    for (int d = 1; d < 64; d <<= 1) {
      float ov = __shfl_xor(v, d);
      int   oi = __shfl_xor(i, d);
      bool take = (ov > v) || (ov == v && oi < i);
      v = take ? ov : v;
      i = take ? oi : i;
    }
    sval[k] = v; sidx[k] = i;
    if (k < 8) {
      used8 |= 1ull << i;
      if (lane == i) cur = -INFINITY;
    }
  }

  float myv = 0.f, myi = 0.f;
#pragma unroll
  for (int k = 0; k < 8; ++k) {
    float pv = __shfl(p, sidx[k]);
    if (lane == k) { myv = pv; myi = (float)sidx[k]; }
  }
  if (lane < 8) {
    out_vals[(size_t)row * 8 + lane] = myv;
    out_idx [(size_t)row * 8 + lane] = myi;
  }

  gate[(size_t)row * NE + lane] = ((used8 >> lane) & 1ull) ? p : 0.0f;

  float ming = INFINITY;
#pragma unroll
  for (int k = 1; k < 9; ++k) ming = fminf(ming, sval[k - 1] - sval[k]);
  if (ming < MARGIN && maxf > 0) {
    unsigned long long cmask = __ballot(l >= sval[7] - MARGIN);
    int n = __popcll(cmask);
    if (n <= MAXCAND) {   // overflow: keep approx result (~1e-9 probability)
      int slot = 0;
      if (lane == 0) slot = atomicAdd(flags, 1);
      slot = __shfl(slot, 0);
      if (slot < maxf) {
        int* rec = flags + 4 + slot * 32;
        if (lane == 0) { rec[0] = row; rec[1] = n; }
        if ((cmask >> lane) & 1ull) {
          int pos = __popcll(cmask & ((1ull << lane) - 1ull));  // ascending e
          rec[2 + pos] = lane;
          ((float*)(rec + 14))[pos] = p;
        }
      }
    }
  }
}

// ---------------- Phase 3: np-exact fixup for flagged rows (unchanged) -------
__global__ __launch_bounds__(64, 1)
void exact_fix(const float* __restrict__ x, const float* __restrict__ w,
               const float* __restrict__ bias, const int* __restrict__ flags,
               int maxf, float* __restrict__ out_vals, float* __restrict__ out_idx,
               float* __restrict__ gate)
{
  __shared__ float xs_[DIM];                 // 8 KB
  __shared__ float wl_[MAXCAND * DIM];       // 96 KB
  __shared__ float exl[MAXCAND];

  int count = flags[0]; if (count > maxf) count = maxf;
  const int lane = threadIdx.x;

  for (int recI = blockIdx.x; recI < count; recI += (int)gridDim.x) {
    const int* rec = flags + 4 + recI * 32;
    const int row = rec[0], n = rec[1];

#pragma unroll
    for (int i = 0; i < 8; ++i)
      ld16_lds(x + (size_t)row * DIM + i * 256 + lane * 4, &xs_[i * 256 + lane * 4]);
    for (int c = 0; c < n; ++c)
#pragma unroll
      for (int i = 0; i < 8; ++i)
        ld16_lds(w + (size_t)rec[2 + c] * DIM + i * 256 + lane * 4,
                 &wl_[c * DIM + i * 256 + lane * 4]);
    asm volatile("s_waitcnt vmcnt(0)" ::: "memory");
    __builtin_amdgcn_s_barrier();

    // np-exact chain: lane = cand*4 + npLane j; reverse in-block, unfused
    const int c = lane >> 2, jj = lane & 3;
    const int cw = (c < n) ? c : 0;
    const float* wrow = &wl_[cw * DIM];
    float a = 0.f;
#pragma unroll 4
    for (int b = 0; b < 128; ++b) {
      const int k = (b << 4) + jj;
      a = a + xs_[k + 12] * wrow[k + 12];
      a = a + xs_[k + 8]  * wrow[k + 8];
      a = a + xs_[k + 4]  * wrow[k + 4];
      a = a + xs_[k]      * wrow[k];
    }
    // SSE3 hadd tree: (L0+L1)+(L2+L3)  (f32 add is commutative-exact)
    float o1 = __shfl_xor(a, 1);
    float s01 = a + o1;
    float o2 = __shfl_xor(s01, 2);
    float tot = (s01 + o2) + bias[rec[2 + cw]];
    if (jj == 0 && c < n) exl[c] = tot;
    __syncthreads();

    if (lane == 0) {
      unsigned used = 0;
      const float* cp = (const float*)(rec + 14);
      for (int k = 0; k < 8; ++k) {
        float best = -INFINITY; int bi = 0;
        for (int c2 = 0; c2 < n; ++c2) {
          bool ok = (((used >> c2) & 1u) == 0u) && (exl[c2] > best);
          best = ok ? exl[c2] : best;
          bi   = ok ? c2      : bi;
        }
        used |= 1u << bi;
        out_vals[(size_t)row * 8 + k] = cp[bi];
        out_idx [(size_t)row * 8 + k] = (float)rec[2 + bi];
      }
      for (int c2 = 0; c2 < n; ++c2)
        gate[(size_t)row * NE + rec[2 + c2]] = ((used >> c2) & 1u) ? cp[c2] : 0.f;
    }
    __syncthreads();
  }
}

extern "C" void kernel_launch(void* const* d_in, const int* in_sizes, int n_in,
                              void* d_out, int out_size, void* d_ws, size_t ws_size,
                              hipStream_t stream) {
  const float* x    = (const float*)d_in[0];
  const float* w    = (const float*)d_in[1];
  const float* bias = (const float*)d_in[2];
  float* out   = (float*)d_out;
  float* vals  = out;                       // 16384*8
  float* idx   = out + (size_t)NROWS * 8;   // 16384*8
  float* dense = out + (size_t)NROWS * 16;  // 16384*64 (P1 logit scratch)
  (void)in_sizes; (void)n_in; (void)out_size;

  const bool use_ws_w = ws_size >= WS_WOFF + (size_t)NE * DIM * 4;  // 1 MB
  int maxf = 0;
  if (ws_size >= 16 + 32 * 4) {
    size_t cap = (ws_size / 4 - 4) / 32;
    if (cap > 2048) cap = 2048;
    if (use_ws_w) { size_t cap2 = (WS_WOFF / 4 - 4) / 32; if (cap > cap2) cap = cap2; }
    maxf = (int)cap;
  }
  int* flags = (int*)d_ws;
  unsigned short* whf = (unsigned short*)((char*)d_ws + WS_WOFF);
  unsigned short* wlf = whf + (size_t)NE * DIM;

  if (use_ws_w) {
    w_split<<<dim3(NE * DIM / 256), dim3(256), 0, stream>>>(w, whf, wlf);
    mfma_logits<true><<<dim3(NROWS / 32), dim3(512), 0, stream>>>(x, w, bias, dense, whf, wlf);
  } else {
    mfma_logits<false><<<dim3(NROWS / 32), dim3(512), 0, stream>>>(x, w, bias, dense, whf, wlf);
  }
  if (maxf > 0) hipMemsetAsync(d_ws, 0, 16, stream);
  finish_kernel<<<dim3(NROWS / 4), dim3(256), 0, stream>>>(dense, vals, idx, flags, maxf);
  if (maxf > 0)
    exact_fix<<<dim3(128), dim3(64), 0, stream>>>(x, w, bias, flags, maxf, vals, idx, dense);
}